// Round 11
// baseline (390.126 us; speedup 1.0000x reference)
//
#include <hip/hip_runtime.h>
#include <math.h>

// Problem constants
#define BN   32768
#define DIM  256
#define KC   1024
#define BN_EPS 1e-5f

// Output layout (floats) in d_out
#define QX_SIZE   (BN * DIM)
#define LOSS0_OFF (QX_SIZE)
#define LOSS1_OFF (QX_SIZE + 1)
#define IDX_OFF   (QX_SIZE + 2)
#define PERP_OFF  (QX_SIZE + 2 + BN)

// Workspace (float offsets) — SMALL SCALARS ONLY. Measured R3..R10: large
// streams in d_ws never L2-cache (FETCH pinned ~250MB); d_in/d_out streams
// cache fully when coalesced (R10: FETCH 20MB on 512MB demand).
#define WS_SUM    0     // 256
#define WS_SUMSQ  256   // 256
#define WS_COUNT  512   // 1
#define WS_LOSS   513   // 1
#define WS_COUNTS 1024  // 1024
#define WS_MU     2048  // 256
#define WS_SCALE  2304  // 256
#define WS_NV     2560  // 1
#define WS_CNORM  3072  // 1024

typedef short bf16x8 __attribute__((ext_vector_type(8)));
typedef float f32x4  __attribute__((ext_vector_type(4)));
typedef float fvec4  __attribute__((ext_vector_type(4)));

static __device__ inline unsigned short f2bf(float f) {
    unsigned int u = __float_as_uint(f);
    return (unsigned short)((u + 0x7FFFu + ((u >> 16) & 1u)) >> 16);
}
static __device__ inline fvec4 nt_ld4(const void* p) {
    return __builtin_nontemporal_load((const fvec4*)p);
}
static __device__ inline void nt_st(float* p, float v) {
    __builtin_nontemporal_store(v, p);
}

// ---------------------------------------------------------------- kernel 1
// Masked stats (LDS-reduced atomics). 128 blocks.
__global__ __launch_bounds__(256) void k_pre(const float* __restrict__ x,
                                             const int* __restrict__ mask,
                                             float* __restrict__ ws) {
    __shared__ float s4[4 * 256];
    __shared__ float q4[4 * 256];
    __shared__ float cntS[4];
    int t = threadIdx.x;
    int c4 = t & 63;
    int rsub = t >> 6;
    float s0=0.f,s1=0.f,s2=0.f,s3=0.f, q0=0.f,q1=0.f,q2=0.f,q3=0.f, cnt=0.f;
    int rbase = blockIdx.x * 4 + rsub;
    for (int i = 0; i < 64; ++i) {
        int r = rbase + i * 512;
        float m = (float)mask[r];
        fvec4 v = nt_ld4(&x[(size_t)r * DIM + c4 * 4]);
        cnt += m;
        float m0 = m*v.x, m1 = m*v.y, m2 = m*v.z, m3 = m*v.w;
        s0 += m0; s1 += m1; s2 += m2; s3 += m3;
        q0 = fmaf(m0, v.x, q0); q1 = fmaf(m1, v.y, q1);
        q2 = fmaf(m2, v.z, q2); q3 = fmaf(m3, v.w, q3);
    }
    int f = c4 * 4;
    s4[rsub * 256 + f + 0] = s0; s4[rsub * 256 + f + 1] = s1;
    s4[rsub * 256 + f + 2] = s2; s4[rsub * 256 + f + 3] = s3;
    q4[rsub * 256 + f + 0] = q0; q4[rsub * 256 + f + 1] = q1;
    q4[rsub * 256 + f + 2] = q2; q4[rsub * 256 + f + 3] = q3;
    if (c4 == 0) cntS[rsub] = cnt;
    __syncthreads();
    float stot = s4[t] + s4[256 + t] + s4[512 + t] + s4[768 + t];
    float qtot = q4[t] + q4[256 + t] + q4[512 + t] + q4[768 + t];
    atomicAdd(&ws[WS_SUM + t], stot);
    atomicAdd(&ws[WS_SUMSQ + t], qtot);
    if (t == 0)
        atomicAdd(&ws[WS_COUNT], cntS[0] + cntS[1] + cntS[2] + cntS[3]);
}

// ---------------------------------------------------------------- kernel 2
__global__ __launch_bounds__(256) void k_finalize(const float* __restrict__ e,
                                                  const float* __restrict__ gamma,
                                                  float* __restrict__ ws) {
    int t = threadIdx.x;
    int b = blockIdx.x;
    if (b == 0) {
        float cnt = ws[WS_COUNT];
        float nv = fmaxf(cnt, 1.f);
        float mu = ws[WS_SUM + t] / nv;
        float var = ws[WS_SUMSQ + t] / nv - mu * mu;
        var = fmaxf(var, 0.f);
        ws[WS_MU + t] = mu;
        ws[WS_SCALE + t] = rsqrtf(var + BN_EPS) * gamma[t];
        if (t == 0) ws[WS_NV] = nv;
    } else {
        int k = (b - 1) * 256 + t;
        float acc = 0.f;
        #pragma unroll 8
        for (int d = 0; d < DIM; ++d) {
            float v = e[(size_t)d * KC + k];
            acc = fmaf(v, v, acc);
        }
        ws[WS_CNORM + k] = acc;
    }
}

// ---------------------------------------------------------------- kernel 2b
// B-fragment build (R5-proven layout/code) into d_out scratch (QX rows
// 0..1023 — overwritten later by k_epi, stream-ordered). 128 blocks.
__global__ __launch_bounds__(256) void k_bfrag(const float* __restrict__ e,
                                               short* __restrict__ bfr) {
    int g = blockIdx.x * 256 + threadIdx.x;   // 0..32767
    int lane = g & 63;
    int kc = (g >> 6) & 7;
    int nt = g >> 9;                          // 0..63
    int n = nt * 16 + (lane & 15);
    int k0 = kc * 32 + ((lane >> 4) & 3) * 8;
    bf16x8 hv, lv;
    #pragma unroll
    for (int j = 0; j < 8; ++j) {
        float v = e[(size_t)(k0 + j) * KC + n];
        unsigned short h = f2bf(v);
        float hf = __uint_as_float((unsigned)h << 16);
        hv[j] = (short)h;
        lv[j] = (short)f2bf(v - hf);
    }
    int base = (((nt * 8 + kc) * 2) * 64 + lane) * 8;
    *(bf16x8*)&bfr[base] = hv;
    *(bf16x8*)&bfr[base + 512] = lv;
}

// ---------------------------------------------------------------- kernel 3
// MFMA main, R11 = R5 execution shape (2 blocks/CU, A staged in-kernel,
// B reg-double-buffered coalesced b128 reads) + R10 memory placement
// (bfr in cacheable d_out pool). Writes idx + counts only.
__global__ __launch_bounds__(256, 2) void k_main_mfma(
        const float* __restrict__ x, const int* __restrict__ mask,
        const short* __restrict__ bfr, const float* __restrict__ beta,
        const float* __restrict__ ws, float* __restrict__ out) {
    __shared__ __align__(16) short afrag[8 * 4 * 2 * 64 * 8];   // 64 KB
    __shared__ float muS[DIM], scS[DIM], btS[DIM];
    __shared__ float cnS[KC];
    __shared__ float redv[64 * 4];
    __shared__ int   redi[64 * 4];

    const int tid = threadIdx.x;
    const int row0 = blockIdx.x * 64;
    const int w = tid >> 6;
    const int lane = tid & 63;
    const int quad = lane >> 4;
    const int col0 = lane & 15;

    muS[tid] = ws[WS_MU + tid];
    scS[tid] = ws[WS_SCALE + tid];
    btS[tid] = beta[tid];
    #pragma unroll
    for (int p = 0; p < 4; ++p)
        cnS[p * 256 + tid] = ws[WS_CNORM + p * 256 + tid];
    __syncthreads();

    // ---- stage A-fragments (normalize + hi/lo split), lane-frag order
    {
        const int mt = w;
        const float* xr = x + (size_t)(row0 + mt * 16 + col0) * DIM;
        const int kq = quad * 8;
        #pragma unroll
        for (int kc = 0; kc < 8; ++kc) {
            int k0 = kc * 32 + kq;
            fvec4 v0 = nt_ld4(xr + k0);
            fvec4 v1 = nt_ld4(xr + k0 + 4);
            float xv[8] = {v0.x, v0.y, v0.z, v0.w, v1.x, v1.y, v1.z, v1.w};
            bf16x8 hv, lv;
            #pragma unroll
            for (int j = 0; j < 8; ++j) {
                float xb = fmaf(xv[j] - muS[k0 + j], scS[k0 + j], btS[k0 + j]);
                unsigned short h = f2bf(xb);
                float hf = __uint_as_float((unsigned)h << 16);
                hv[j] = (short)h;
                lv[j] = (short)f2bf(xb - hf);
            }
            int base = (((kc * 4 + mt) * 2) * 64 + lane) * 8;
            *(bf16x8*)&afrag[base] = hv;
            *(bf16x8*)&afrag[base + 512] = lv;
        }
    }
    __syncthreads();

    // ---- GEMM: wave w covers codes [w*256, w*256+256), 4 ngroups of 64
    float minv[16];
    int   mini[16];
    #pragma unroll
    for (int i = 0; i < 16; ++i) { minv[i] = 3.4e38f; mini[i] = 0; }

    for (int ng = 0; ng < 4; ++ng) {
        f32x4 acc[4][4];
        #pragma unroll
        for (int mt = 0; mt < 4; ++mt)
            #pragma unroll
            for (int nt = 0; nt < 4; ++nt)
                acc[mt][nt] = (f32x4){0.f, 0.f, 0.f, 0.f};

        bf16x8 bh[2][4], bl[2][4];
        #pragma unroll
        for (int nt = 0; nt < 4; ++nt) {
            const short* bp = bfr +
                (size_t)((((w * 16 + ng * 4 + nt) * 8 + 0) * 2) * 64 + lane) * 8;
            bh[0][nt] = *(const bf16x8*)bp;
            bl[0][nt] = *(const bf16x8*)(bp + 512);
        }

        #pragma unroll
        for (int kc = 0; kc < 8; ++kc) {
            const int cur = kc & 1, nxt = cur ^ 1;
            if (kc < 7) {
                #pragma unroll
                for (int nt = 0; nt < 4; ++nt) {
                    const short* bp = bfr +
                        (size_t)((((w * 16 + ng * 4 + nt) * 8 + kc + 1) * 2) * 64 + lane) * 8;
                    bh[nxt][nt] = *(const bf16x8*)bp;
                    bl[nxt][nt] = *(const bf16x8*)(bp + 512);
                }
            }
            bf16x8 ah[4], al[4];
            #pragma unroll
            for (int mt = 0; mt < 4; ++mt) {
                int base = (((kc * 4 + mt) * 2) * 64 + lane) * 8;
                ah[mt] = *(const bf16x8*)&afrag[base];
                al[mt] = *(const bf16x8*)&afrag[base + 512];
            }
            #pragma unroll
            for (int nt = 0; nt < 4; ++nt)
                #pragma unroll
                for (int mt = 0; mt < 4; ++mt) {
                    acc[mt][nt] = __builtin_amdgcn_mfma_f32_16x16x32_bf16(
                        ah[mt], bh[cur][nt], acc[mt][nt], 0, 0, 0);
                    acc[mt][nt] = __builtin_amdgcn_mfma_f32_16x16x32_bf16(
                        ah[mt], bl[cur][nt], acc[mt][nt], 0, 0, 0);
                    acc[mt][nt] = __builtin_amdgcn_mfma_f32_16x16x32_bf16(
                        al[mt], bh[cur][nt], acc[mt][nt], 0, 0, 0);
                }
        }
        // scores + running min (k ascending -> first-min tie semantics)
        #pragma unroll
        for (int nt = 0; nt < 4; ++nt) {
            int kcode = w * 256 + ng * 64 + nt * 16 + col0;
            float cn = cnS[kcode];
            #pragma unroll
            for (int mt = 0; mt < 4; ++mt)
                #pragma unroll
                for (int r = 0; r < 4; ++r) {
                    float s = fmaf(-2.f, acc[mt][nt][r], cn);
                    int slot = mt * 4 + r;
                    if (s < minv[slot]) { minv[slot] = s; mini[slot] = kcode; }
                }
        }
    }

    // ---- in-wave argmin reduce (16-lane butterfly over col0), then LDS
    #pragma unroll
    for (int s = 0; s < 16; ++s) {
        float v = minv[s];
        int   ii = mini[s];
        #pragma unroll
        for (int m2 = 1; m2 < 16; m2 <<= 1) {
            float v2 = __shfl_xor(v, m2, 64);
            int   i2 = __shfl_xor(ii, m2, 64);
            if (v2 < v || (v2 == v && i2 < ii)) { v = v2; ii = i2; }
        }
        int row = (s >> 2) * 16 + quad * 4 + (s & 3);
        if (col0 == 0) { redv[row * 4 + w] = v; redi[row * 4 + w] = ii; }
    }
    __syncthreads();
    if (tid < 64) {
        float bv = redv[tid * 4];
        int bi = redi[tid * 4];
        #pragma unroll
        for (int t2 = 1; t2 < 4; ++t2) {
            float v = redv[tid * 4 + t2];
            int ii = redi[tid * 4 + t2];
            if (v < bv || (v == bv && ii < bi)) { bv = v; bi = ii; }
        }
        int m = mask[row0 + tid];
        out[IDX_OFF + row0 + tid] = m ? (float)bi : -1.0f;
        if (m) atomicAdd((float*)&ws[WS_COUNTS + bi], 1.0f);
    }
}

// ---------------------------------------------------------------- kernel 3b
// Epilogue: recompute xb exactly in f32 from x, gather q from e rows
// (cached), write quantized rows (overwrites bfr region last), losses.
__global__ __launch_bounds__(256) void k_epi(const float* __restrict__ x,
                                             const float* __restrict__ e,
                                             const float* __restrict__ beta,
                                             const float* __restrict__ ws,
                                             float* __restrict__ out) {
    __shared__ float muS[DIM], scS[DIM], btS[DIM];
    __shared__ int   idxS[64];
    __shared__ float mskS[64];
    __shared__ float wred[4];
    const int tid = threadIdx.x;
    const int row0 = blockIdx.x * 64;

    muS[tid] = ws[WS_MU + tid];
    scS[tid] = ws[WS_SCALE + tid];
    btS[tid] = beta[tid];
    if (tid < 64) {
        float fi = out[IDX_OFF + row0 + tid];
        int m = (fi >= 0.f) ? 1 : 0;
        idxS[tid] = m ? (int)fi : 0;
        mskS[tid] = (float)m;
    }
    __syncthreads();

    float lacc = 0.f;
    float mu = muS[tid], sc = scS[tid], bt = btS[tid];
    const float* erow = e + (size_t)tid * KC;   // feature d = tid
    for (int r = 0; r < 64; ++r) {
        float m = mskS[r];
        float q = (m != 0.f) ? erow[idxS[r]] : 0.f;
        float v = x[(size_t)(row0 + r) * DIM + tid];
        float xb = fmaf(v - mu, sc, bt);
        float diff = xb - q;
        lacc = fmaf(m * diff, diff, lacc);
        nt_st(&out[(size_t)(row0 + r) * DIM + tid], q);
    }
    #pragma unroll
    for (int off = 32; off > 0; off >>= 1) lacc += __shfl_down(lacc, off, 64);
    if ((tid & 63) == 0) wred[tid >> 6] = lacc;
    __syncthreads();
    if (tid == 0)
        atomicAdd((float*)&ws[WS_LOSS], wred[0] + wred[1] + wred[2] + wred[3]);
}

// ---------------------------------------------------------------- kernel 4
__global__ __launch_bounds__(256) void k_final(const float* __restrict__ ws,
                                               float* __restrict__ out) {
    int t = threadIdx.x;
    __shared__ float wr[4];
    float nv = ws[WS_NV];
    float acc = 0.f;
    for (int j = t; j < KC; j += 256) {
        float p = ws[WS_COUNTS + j] / nv;
        acc = fmaf(p, logf(p + 1e-10f), acc);
    }
    #pragma unroll
    for (int off = 32; off > 0; off >>= 1) acc += __shfl_down(acc, off, 64);
    if ((t & 63) == 0) wr[t >> 6] = acc;
    __syncthreads();
    if (t == 0) {
        float ent = wr[0] + wr[1] + wr[2] + wr[3];
        float loss = ws[WS_LOSS] / (nv * (float)DIM);
        out[LOSS0_OFF] = loss;
        out[LOSS1_OFF] = loss;
        out[PERP_OFF] = expf(-ent);
    }
}

// ---------------------------------------------------------------- launch
extern "C" void kernel_launch(void* const* d_in, const int* in_sizes, int n_in,
                              void* d_out, int out_size, void* d_ws, size_t ws_size,
                              hipStream_t stream) {
    const float* x     = (const float*)d_in[0];
    const int*   amask = (const int*)d_in[1];
    const float* e     = (const float*)d_in[2];
    const float* gamma = (const float*)d_in[3];
    const float* beta  = (const float*)d_in[4];
    float* out = (float*)d_out;
    float* ws  = (float*)d_ws;

    (void)hipMemsetAsync(d_ws, 0, 8192, stream);

    // bfr lives in the CACHEABLE d_out pool (QX rows 0..1023 as scratch);
    // k_epi overwrites that region only after k_main finishes (stream order).
    short* bfr = (short*)out;
    k_pre<<<128, 256, 0, stream>>>(x, amask, ws);
    k_finalize<<<5, 256, 0, stream>>>(e, gamma, ws);
    k_bfrag<<<128, 256, 0, stream>>>(e, bfr);
    k_main_mfma<<<BN / 64, 256, 0, stream>>>(x, amask, bfr, beta, ws, out);
    k_epi<<<BN / 64, 256, 0, stream>>>(x, e, beta, ws, out);
    k_final<<<1, 256, 0, stream>>>(ws, out);
}

// Round 12
// 384.524 us; speedup vs baseline: 1.0146x; 1.0146x over previous
//
#include <hip/hip_runtime.h>
#include <math.h>

// Problem constants
#define BN   32768
#define DIM  256
#define KC   1024
#define BN_EPS 1e-5f

// Output layout (floats) in d_out
#define QX_SIZE   (BN * DIM)
#define LOSS0_OFF (QX_SIZE)
#define LOSS1_OFF (QX_SIZE + 1)
#define IDX_OFF   (QX_SIZE + 2)
#define PERP_OFF  (QX_SIZE + 2 + BN)

// Workspace (float offsets) — SMALL SCALARS ONLY.
// Placement law (R2..R11 measured): only d_in buffers give L2-cacheable
// reuse; d_ws AND d_out reads behave uncached (~250MB FETCH + phantom
// WRITE at ~1.65 TB/s). So B streams directly from e, A is built in-kernel.
#define WS_SUM    0     // 256
#define WS_SUMSQ  256   // 256
#define WS_COUNT  512   // 1
#define WS_LOSS   513   // 1
#define WS_COUNTS 1024  // 1024
#define WS_MU     2048  // 256
#define WS_SCALE  2304  // 256
#define WS_NV     2560  // 1
#define WS_CNORM  3072  // 1024

typedef short bf16x8 __attribute__((ext_vector_type(8)));
typedef float f32x4  __attribute__((ext_vector_type(4)));
typedef float fvec4  __attribute__((ext_vector_type(4)));

static __device__ inline unsigned short f2bf(float f) {
    unsigned int u = __float_as_uint(f);
    return (unsigned short)((u + 0x7FFFu + ((u >> 16) & 1u)) >> 16);
}
static __device__ inline fvec4 nt_ld4(const void* p) {
    return __builtin_nontemporal_load((const fvec4*)p);
}
static __device__ inline void nt_st(float* p, float v) {
    __builtin_nontemporal_store(v, p);
}

// ---------------------------------------------------------------- kernel 1
// Masked stats (LDS-reduced atomics). 128 blocks.
__global__ __launch_bounds__(256) void k_pre(const float* __restrict__ x,
                                             const int* __restrict__ mask,
                                             float* __restrict__ ws) {
    __shared__ float s4[4 * 256];
    __shared__ float q4[4 * 256];
    __shared__ float cntS[4];
    int t = threadIdx.x;
    int c4 = t & 63;
    int rsub = t >> 6;
    float s0=0.f,s1=0.f,s2=0.f,s3=0.f, q0=0.f,q1=0.f,q2=0.f,q3=0.f, cnt=0.f;
    int rbase = blockIdx.x * 4 + rsub;
    for (int i = 0; i < 64; ++i) {
        int r = rbase + i * 512;
        float m = (float)mask[r];
        fvec4 v = nt_ld4(&x[(size_t)r * DIM + c4 * 4]);
        cnt += m;
        float m0 = m*v.x, m1 = m*v.y, m2 = m*v.z, m3 = m*v.w;
        s0 += m0; s1 += m1; s2 += m2; s3 += m3;
        q0 = fmaf(m0, v.x, q0); q1 = fmaf(m1, v.y, q1);
        q2 = fmaf(m2, v.z, q2); q3 = fmaf(m3, v.w, q3);
    }
    int f = c4 * 4;
    s4[rsub * 256 + f + 0] = s0; s4[rsub * 256 + f + 1] = s1;
    s4[rsub * 256 + f + 2] = s2; s4[rsub * 256 + f + 3] = s3;
    q4[rsub * 256 + f + 0] = q0; q4[rsub * 256 + f + 1] = q1;
    q4[rsub * 256 + f + 2] = q2; q4[rsub * 256 + f + 3] = q3;
    if (c4 == 0) cntS[rsub] = cnt;
    __syncthreads();
    float stot = s4[t] + s4[256 + t] + s4[512 + t] + s4[768 + t];
    float qtot = q4[t] + q4[256 + t] + q4[512 + t] + q4[768 + t];
    atomicAdd(&ws[WS_SUM + t], stot);
    atomicAdd(&ws[WS_SUMSQ + t], qtot);
    if (t == 0)
        atomicAdd(&ws[WS_COUNT], cntS[0] + cntS[1] + cntS[2] + cntS[3]);
}

// ---------------------------------------------------------------- kernel 2
__global__ __launch_bounds__(256) void k_finalize(const float* __restrict__ e,
                                                  const float* __restrict__ gamma,
                                                  float* __restrict__ ws) {
    int t = threadIdx.x;
    int b = blockIdx.x;
    if (b == 0) {
        float cnt = ws[WS_COUNT];
        float nv = fmaxf(cnt, 1.f);
        float mu = ws[WS_SUM + t] / nv;
        float var = ws[WS_SUMSQ + t] / nv - mu * mu;
        var = fmaxf(var, 0.f);
        ws[WS_MU + t] = mu;
        ws[WS_SCALE + t] = rsqrtf(var + BN_EPS) * gamma[t];
        if (t == 0) ws[WS_NV] = nv;
    } else {
        int k = (b - 1) * 256 + t;
        float acc = 0.f;
        #pragma unroll 8
        for (int d = 0; d < DIM; ++d) {
            float v = e[(size_t)d * KC + k];
            acc = fmaf(v, v, acc);
        }
        ws[WS_CNORM + k] = acc;
    }
}

// ---------------------------------------------------------------- kernel 3
// MFMA main, R12 = R10's proven B-direct-from-e inner loop at 2 blocks/CU:
// 32 rows/block (A-frags 32 KB in-kernel), wave-private single-buffer B
// LDS chunks (8 KB x 4), register prefetch across chunks. Grid 1024.
#define RBM 32
__global__ __launch_bounds__(256, 2) void k_main_mfma(
        const float* __restrict__ x, const int* __restrict__ mask,
        const float* __restrict__ e, const float* __restrict__ beta,
        const float* __restrict__ ws, float* __restrict__ out) {
    __shared__ __align__(16) short afrag[8 * 2 * 2 * 64 * 8];   // 32 KB
    __shared__ __align__(16) float Bs[4][32 * 64];              // 32 KB
    __shared__ float muS[DIM], scS[DIM], btS[DIM];
    __shared__ float redv[RBM * 4];
    __shared__ int   redi[RBM * 4];

    const int tid = threadIdx.x;
    const int row0 = blockIdx.x * RBM;
    const int w = tid >> 6;
    const int lane = tid & 63;
    const int quad = lane >> 4;
    const int col0 = lane & 15;

    muS[tid] = ws[WS_MU + tid];
    scS[tid] = ws[WS_SCALE + tid];
    btS[tid] = beta[tid];
    __syncthreads();

    // ---- stage A-fragments: wave w stages mtile (w>>1), kc half (w&1)
    {
        const int mt = w >> 1;
        const float* xr = x + (size_t)(row0 + mt * 16 + col0) * DIM;
        const int kq = quad * 8;
        #pragma unroll
        for (int kk = 0; kk < 4; ++kk) {
            int kc = (w & 1) * 4 + kk;
            int k0 = kc * 32 + kq;
            fvec4 v0 = nt_ld4(xr + k0);
            fvec4 v1 = nt_ld4(xr + k0 + 4);
            float xv[8] = {v0.x, v0.y, v0.z, v0.w, v1.x, v1.y, v1.z, v1.w};
            bf16x8 hv, lv;
            #pragma unroll
            for (int j = 0; j < 8; ++j) {
                float xb = fmaf(xv[j] - muS[k0 + j], scS[k0 + j], btS[k0 + j]);
                unsigned short h = f2bf(xb);
                float hf = __uint_as_float((unsigned)h << 16);
                hv[j] = (short)h;
                lv[j] = (short)f2bf(xb - hf);
            }
            int base = (((kc * 2 + mt) * 2) * 64 + lane) * 8;
            *(bf16x8*)&afrag[base] = hv;
            *(bf16x8*)&afrag[base + 512] = lv;
        }
    }
    __syncthreads();

    const fvec4* e4 = (const fvec4*)e;   // 256 fvec4 per d-row
    float* bsw = &Bs[w][0];

    float minv[8];
    int   mini[8];
    #pragma unroll
    for (int i = 0; i < 8; ++i) { minv[i] = 3.4e38f; mini[i] = 0; }

    // prefetch (ng=0, kc=0): K-rows 0..31, codes w*256..w*256+63 (coalesced)
    fvec4 raw[2][8];
    #pragma unroll
    for (int p = 0; p < 8; ++p) {
        int f = p * 64 + lane;
        raw[0][p] = e4[(size_t)(f >> 4) * 256 + w * 64 + (f & 15)];
    }

    for (int ng = 0; ng < 4; ++ng) {
        f32x4 acc[2][4];
        #pragma unroll
        for (int mt = 0; mt < 2; ++mt)
            #pragma unroll
            for (int nt = 0; nt < 4; ++nt)
                acc[mt][nt] = (f32x4){0.f, 0.f, 0.f, 0.f};

        #pragma unroll
        for (int kc = 0; kc < 8; ++kc) {
            const int buf = kc & 1;
            // commit current chunk to this wave's private LDS (no barrier;
            // same-wave LDS ordering enforced by compiler waits)
            {
                fvec4* b4 = (fvec4*)bsw;
                #pragma unroll
                for (int p = 0; p < 8; ++p)
                    b4[p * 64 + lane] = raw[buf][p];
            }
            // prefetch next chunk (coalesced rows of e) into other reg set
            if (!(ng == 3 && kc == 7)) {
                int nng = (kc == 7) ? ng + 1 : ng;
                int nkc = (kc == 7) ? 0 : kc + 1;
                #pragma unroll
                for (int p = 0; p < 8; ++p) {
                    int f = p * 64 + lane;
                    raw[buf ^ 1][p] =
                        e4[(size_t)(nkc * 32 + (f >> 4)) * 256 + w * 64 + nng * 16 + (f & 15)];
                }
            }
            // A fragments for this kc
            bf16x8 ah[2], al[2];
            #pragma unroll
            for (int mt = 0; mt < 2; ++mt) {
                int base = (((kc * 2 + mt) * 2) * 64 + lane) * 8;
                ah[mt] = *(const bf16x8*)&afrag[base];
                al[mt] = *(const bf16x8*)&afrag[base + 512];
            }
            // B fragments from LDS + truncate-split, then 3-pass MFMA
            #pragma unroll
            for (int nt = 0; nt < 4; ++nt) {
                bf16x8 bh, bl;
                #pragma unroll
                for (int j = 0; j < 8; ++j) {
                    float v = bsw[(quad * 8 + j) * 64 + nt * 16 + col0];
                    unsigned u = __float_as_uint(v);
                    bh[j] = (short)(u >> 16);
                    float lo = v - __uint_as_float(u & 0xffff0000u);
                    bl[j] = (short)(__float_as_uint(lo) >> 16);
                }
                #pragma unroll
                for (int mt = 0; mt < 2; ++mt) {
                    acc[mt][nt] = __builtin_amdgcn_mfma_f32_16x16x32_bf16(
                        ah[mt], bh, acc[mt][nt], 0, 0, 0);
                    acc[mt][nt] = __builtin_amdgcn_mfma_f32_16x16x32_bf16(
                        ah[mt], bl, acc[mt][nt], 0, 0, 0);
                    acc[mt][nt] = __builtin_amdgcn_mfma_f32_16x16x32_bf16(
                        al[mt], bh, acc[mt][nt], 0, 0, 0);
                }
            }
        }
        // scores + running min (k ascending -> first-min tie semantics)
        #pragma unroll
        for (int nt = 0; nt < 4; ++nt) {
            int kcode = w * 256 + ng * 64 + nt * 16 + col0;
            float cn = ws[WS_CNORM + kcode];
            #pragma unroll
            for (int mt = 0; mt < 2; ++mt)
                #pragma unroll
                for (int r = 0; r < 4; ++r) {
                    float s = fmaf(-2.f, acc[mt][nt][r], cn);
                    int slot = mt * 4 + r;
                    if (s < minv[slot]) { minv[slot] = s; mini[slot] = kcode; }
                }
        }
    }

    // ---- in-wave argmin reduce (16-lane butterfly over col0), then LDS
    #pragma unroll
    for (int s = 0; s < 8; ++s) {
        float v = minv[s];
        int   ii = mini[s];
        #pragma unroll
        for (int m2 = 1; m2 < 16; m2 <<= 1) {
            float v2 = __shfl_xor(v, m2, 64);
            int   i2 = __shfl_xor(ii, m2, 64);
            if (v2 < v || (v2 == v && i2 < ii)) { v = v2; ii = i2; }
        }
        int row = (s >> 2) * 16 + quad * 4 + (s & 3);   // mt*16 + quad*4 + r
        if (col0 == 0) { redv[row * 4 + w] = v; redi[row * 4 + w] = ii; }
    }
    __syncthreads();
    if (tid < RBM) {
        float bv = redv[tid * 4];
        int bi = redi[tid * 4];
        #pragma unroll
        for (int t2 = 1; t2 < 4; ++t2) {
            float v = redv[tid * 4 + t2];
            int ii = redi[tid * 4 + t2];
            if (v < bv || (v == bv && ii < bi)) { bv = v; bi = ii; }
        }
        int m = mask[row0 + tid];
        out[IDX_OFF + row0 + tid] = m ? (float)bi : -1.0f;
        if (m) atomicAdd((float*)&ws[WS_COUNTS + bi], 1.0f);
    }
}

// ---------------------------------------------------------------- kernel 3b
// Epilogue (R11-proven): recompute xb exactly in f32 from x, gather q from
// e rows (L2-cached d_in), write quantized rows, losses. 64 rows/block.
__global__ __launch_bounds__(256) void k_epi(const float* __restrict__ x,
                                             const float* __restrict__ e,
                                             const float* __restrict__ beta,
                                             const float* __restrict__ ws,
                                             float* __restrict__ out) {
    __shared__ float muS[DIM], scS[DIM], btS[DIM];
    __shared__ int   idxS[64];
    __shared__ float mskS[64];
    __shared__ float wred[4];
    const int tid = threadIdx.x;
    const int row0 = blockIdx.x * 64;

    muS[tid] = ws[WS_MU + tid];
    scS[tid] = ws[WS_SCALE + tid];
    btS[tid] = beta[tid];
    if (tid < 64) {
        float fi = out[IDX_OFF + row0 + tid];
        int m = (fi >= 0.f) ? 1 : 0;
        idxS[tid] = m ? (int)fi : 0;
        mskS[tid] = (float)m;
    }
    __syncthreads();

    float lacc = 0.f;
    float mu = muS[tid], sc = scS[tid], bt = btS[tid];
    const float* erow = e + (size_t)tid * KC;   // feature d = tid
    for (int r = 0; r < 64; ++r) {
        float m = mskS[r];
        float q = (m != 0.f) ? erow[idxS[r]] : 0.f;
        float v = x[(size_t)(row0 + r) * DIM + tid];
        float xb = fmaf(v - mu, sc, bt);
        float diff = xb - q;
        lacc = fmaf(m * diff, diff, lacc);
        nt_st(&out[(size_t)(row0 + r) * DIM + tid], q);
    }
    #pragma unroll
    for (int off = 32; off > 0; off >>= 1) lacc += __shfl_down(lacc, off, 64);
    if ((tid & 63) == 0) wred[tid >> 6] = lacc;
    __syncthreads();
    if (tid == 0)
        atomicAdd((float*)&ws[WS_LOSS], wred[0] + wred[1] + wred[2] + wred[3]);
}

// ---------------------------------------------------------------- kernel 4
__global__ __launch_bounds__(256) void k_final(const float* __restrict__ ws,
                                               float* __restrict__ out) {
    int t = threadIdx.x;
    __shared__ float wr[4];
    float nv = ws[WS_NV];
    float acc = 0.f;
    for (int j = t; j < KC; j += 256) {
        float p = ws[WS_COUNTS + j] / nv;
        acc = fmaf(p, logf(p + 1e-10f), acc);
    }
    #pragma unroll
    for (int off = 32; off > 0; off >>= 1) acc += __shfl_down(acc, off, 64);
    if ((t & 63) == 0) wr[t >> 6] = acc;
    __syncthreads();
    if (t == 0) {
        float ent = wr[0] + wr[1] + wr[2] + wr[3];
        float loss = ws[WS_LOSS] / (nv * (float)DIM);
        out[LOSS0_OFF] = loss;
        out[LOSS1_OFF] = loss;
        out[PERP_OFF] = expf(-ent);
    }
}

// ---------------------------------------------------------------- launch
extern "C" void kernel_launch(void* const* d_in, const int* in_sizes, int n_in,
                              void* d_out, int out_size, void* d_ws, size_t ws_size,
                              hipStream_t stream) {
    const float* x     = (const float*)d_in[0];
    const int*   amask = (const int*)d_in[1];
    const float* e     = (const float*)d_in[2];
    const float* gamma = (const float*)d_in[3];
    const float* beta  = (const float*)d_in[4];
    float* out = (float*)d_out;
    float* ws  = (float*)d_ws;

    (void)hipMemsetAsync(d_ws, 0, 8192, stream);

    k_pre<<<128, 256, 0, stream>>>(x, amask, ws);
    k_finalize<<<5, 256, 0, stream>>>(e, gamma, ws);
    k_main_mfma<<<BN / RBM, 256, 0, stream>>>(x, amask, e, beta, ws, out);
    k_epi<<<BN / 64, 256, 0, stream>>>(x, e, beta, ws, out);
    k_final<<<1, 256, 0, stream>>>(ws, out);
}

// Round 13
// 320.973 us; speedup vs baseline: 1.2154x; 1.1980x over previous
//
#include <hip/hip_runtime.h>
#include <math.h>

// Problem constants
#define BN   32768
#define DIM  256
#define KC   1024
#define BN_EPS 1e-5f

// Output layout (floats) in d_out
#define QX_SIZE   (BN * DIM)
#define LOSS0_OFF (QX_SIZE)
#define LOSS1_OFF (QX_SIZE + 1)
#define IDX_OFF   (QX_SIZE + 2)
#define PERP_OFF  (QX_SIZE + 2 + BN)

// Workspace (float offsets) — SMALL SCALARS ONLY.
// Placement law (R2..R12 measured): only d_in buffers give L2-cacheable
// reuse; d_ws and d_out reads behave uncached. B streams from e; A is
// built in-kernel from x.
#define WS_SUM    0     // 256
#define WS_SUMSQ  256   // 256
#define WS_COUNT  512   // 1
#define WS_LOSS   513   // 1
#define WS_COUNTS 1024  // 1024
#define WS_MU     2048  // 256
#define WS_SCALE  2304  // 256
#define WS_NV     2560  // 1
#define WS_CNORM  3072  // 1024

typedef short bf16x8 __attribute__((ext_vector_type(8)));
typedef float f32x4  __attribute__((ext_vector_type(4)));
typedef float fvec4  __attribute__((ext_vector_type(4)));

static __device__ inline unsigned short f2bf(float f) {
    unsigned int u = __float_as_uint(f);
    return (unsigned short)((u + 0x7FFFu + ((u >> 16) & 1u)) >> 16);
}
static __device__ inline fvec4 nt_ld4(const void* p) {
    return __builtin_nontemporal_load((const fvec4*)p);
}
static __device__ inline void nt_st(float* p, float v) {
    __builtin_nontemporal_store(v, p);
}

// ---------------------------------------------------------------- kernel 1
// Masked stats (LDS-reduced atomics). 128 blocks.
__global__ __launch_bounds__(256) void k_pre(const float* __restrict__ x,
                                             const int* __restrict__ mask,
                                             float* __restrict__ ws) {
    __shared__ float s4[4 * 256];
    __shared__ float q4[4 * 256];
    __shared__ float cntS[4];
    int t = threadIdx.x;
    int c4 = t & 63;
    int rsub = t >> 6;
    float s0=0.f,s1=0.f,s2=0.f,s3=0.f, q0=0.f,q1=0.f,q2=0.f,q3=0.f, cnt=0.f;
    int rbase = blockIdx.x * 4 + rsub;
    for (int i = 0; i < 64; ++i) {
        int r = rbase + i * 512;
        float m = (float)mask[r];
        fvec4 v = nt_ld4(&x[(size_t)r * DIM + c4 * 4]);
        cnt += m;
        float m0 = m*v.x, m1 = m*v.y, m2 = m*v.z, m3 = m*v.w;
        s0 += m0; s1 += m1; s2 += m2; s3 += m3;
        q0 = fmaf(m0, v.x, q0); q1 = fmaf(m1, v.y, q1);
        q2 = fmaf(m2, v.z, q2); q3 = fmaf(m3, v.w, q3);
    }
    int f = c4 * 4;
    s4[rsub * 256 + f + 0] = s0; s4[rsub * 256 + f + 1] = s1;
    s4[rsub * 256 + f + 2] = s2; s4[rsub * 256 + f + 3] = s3;
    q4[rsub * 256 + f + 0] = q0; q4[rsub * 256 + f + 1] = q1;
    q4[rsub * 256 + f + 2] = q2; q4[rsub * 256 + f + 3] = q3;
    if (c4 == 0) cntS[rsub] = cnt;
    __syncthreads();
    float stot = s4[t] + s4[256 + t] + s4[512 + t] + s4[768 + t];
    float qtot = q4[t] + q4[256 + t] + q4[512 + t] + q4[768 + t];
    atomicAdd(&ws[WS_SUM + t], stot);
    atomicAdd(&ws[WS_SUMSQ + t], qtot);
    if (t == 0)
        atomicAdd(&ws[WS_COUNT], cntS[0] + cntS[1] + cntS[2] + cntS[3]);
}

// ---------------------------------------------------------------- kernel 2
__global__ __launch_bounds__(256) void k_finalize(const float* __restrict__ e,
                                                  const float* __restrict__ gamma,
                                                  float* __restrict__ ws) {
    int t = threadIdx.x;
    int b = blockIdx.x;
    if (b == 0) {
        float cnt = ws[WS_COUNT];
        float nv = fmaxf(cnt, 1.f);
        float mu = ws[WS_SUM + t] / nv;
        float var = ws[WS_SUMSQ + t] / nv - mu * mu;
        var = fmaxf(var, 0.f);
        ws[WS_MU + t] = mu;
        ws[WS_SCALE + t] = rsqrtf(var + BN_EPS) * gamma[t];
        if (t == 0) ws[WS_NV] = nv;
    } else {
        int k = (b - 1) * 256 + t;
        float acc = 0.f;
        #pragma unroll 8
        for (int d = 0; d < DIM; ++d) {
            float v = e[(size_t)d * KC + k];
            acc = fmaf(v, v, acc);
        }
        ws[WS_CNORM + k] = acc;
    }
}

// ---------------------------------------------------------------- kernel 3
// MFMA main, R13 = R10's proven structure (64 rows/block, grid 512,
// 1 block/CU, wave-private LDS B from e) with three fixes:
//  (1) prefetch ring depth 2 (2x outstanding e-loads vs R10),
//  (2) XOR-swizzled B LDS layout: 4-way bank conflict -> free 2-way,
//  (3) A staged in-kernel from x (drops gfrag round-trip + k_afrag).
__global__ __launch_bounds__(256, 1) void k_main_mfma(
        const float* __restrict__ x, const int* __restrict__ mask,
        const float* __restrict__ e, const float* __restrict__ beta,
        const float* __restrict__ ws, float* __restrict__ out) {
    __shared__ __align__(16) short afrag[8 * 4 * 2 * 64 * 8];   // 64 KB
    __shared__ __align__(16) float Bs[4][2][2048];              // 64 KB
    __shared__ float muS[DIM], scS[DIM], btS[DIM];
    __shared__ float cnS[KC];
    __shared__ float redv[64 * 4];
    __shared__ int   redi[64 * 4];

    const int tid = threadIdx.x;
    const int row0 = blockIdx.x * 64;
    const int w = tid >> 6;
    const int lane = tid & 63;
    const int quad = lane >> 4;
    const int col0 = lane & 15;

    muS[tid] = ws[WS_MU + tid];
    scS[tid] = ws[WS_SCALE + tid];
    btS[tid] = beta[tid];
    #pragma unroll
    for (int p = 0; p < 4; ++p)
        cnS[p * 256 + tid] = ws[WS_CNORM + p * 256 + tid];
    __syncthreads();

    // ---- stage A-fragments in-kernel (normalize + hi/lo split)
    {
        const int mt = w;
        const float* xr = x + (size_t)(row0 + mt * 16 + col0) * DIM;
        const int kq = quad * 8;
        #pragma unroll
        for (int kc = 0; kc < 8; ++kc) {
            int k0 = kc * 32 + kq;
            fvec4 v0 = nt_ld4(xr + k0);
            fvec4 v1 = nt_ld4(xr + k0 + 4);
            float xv[8] = {v0.x, v0.y, v0.z, v0.w, v1.x, v1.y, v1.z, v1.w};
            bf16x8 hv, lv;
            #pragma unroll
            for (int j = 0; j < 8; ++j) {
                float xb = fmaf(xv[j] - muS[k0 + j], scS[k0 + j], btS[k0 + j]);
                unsigned short h = f2bf(xb);
                float hf = __uint_as_float((unsigned)h << 16);
                hv[j] = (short)h;
                lv[j] = (short)f2bf(xb - hf);
            }
            int base = (((kc * 4 + mt) * 2) * 64 + lane) * 8;
            *(bf16x8*)&afrag[base] = hv;
            *(bf16x8*)&afrag[base + 512] = lv;
        }
    }
    __syncthreads();

    const fvec4* e4 = (const fvec4*)e;   // 256 fvec4 per d-row
    const int swz = (quad & 1) * 4;      // read-side bank swizzle (const/lane)

    float minv[16];
    int   mini[16];
    #pragma unroll
    for (int i = 0; i < 16; ++i) { minv[i] = 3.4e38f; mini[i] = 0; }

    // chunk ci = ng*8+kc: k-rows kc*32..+31, codes w*256+ng*64..+63.
    // ring of 3 register buffers; depth-2 prefetch (16 fvec4 in flight).
    fvec4 raw[3][8];
    #pragma unroll
    for (int p = 0; p < 8; ++p) {
        int f = p * 64 + lane;
        raw[0][p] = e4[(size_t)((f >> 4)) * 256 + w * 64 + (f & 15)];          // ci=0
        raw[1][p] = e4[(size_t)(32 + (f >> 4)) * 256 + w * 64 + (f & 15)];     // ci=1
    }

    f32x4 acc[4][4];
    #pragma unroll
    for (int mt = 0; mt < 4; ++mt)
        #pragma unroll
        for (int nt = 0; nt < 4; ++nt)
            acc[mt][nt] = (f32x4){0.f, 0.f, 0.f, 0.f};

    #pragma unroll
    for (int ng = 0; ng < 4; ++ng) {
        #pragma unroll
        for (int kc = 0; kc < 8; ++kc) {
            const int ci = ng * 8 + kc;
            const int buf = ci % 3;
            float* bsw = &Bs[w][ci & 1][0];
            // commit chunk ci to wave-private LDS, XOR-swizzled fvec4 slots
            {
                fvec4* b4 = (fvec4*)bsw;
                #pragma unroll
                for (int p = 0; p < 8; ++p) {
                    int f = p * 64 + lane;
                    int row = f >> 4;
                    int c4 = f & 15;
                    b4[row * 16 + (c4 ^ (((row >> 3) & 1) * 4))] = raw[buf][p];
                }
            }
            // depth-2 prefetch: issue chunk ci+2
            if (ci + 2 < 32) {
                const int nci = ci + 2;
                const int nng = nci >> 3, nkc = nci & 7;
                #pragma unroll
                for (int p = 0; p < 8; ++p) {
                    int f = p * 64 + lane;
                    raw[nci % 3][p] =
                        e4[(size_t)(nkc * 32 + (f >> 4)) * 256 + w * 64 + nng * 16 + (f & 15)];
                }
            }
            // A fragments for this kc
            bf16x8 ah[4], al[4];
            #pragma unroll
            for (int mt = 0; mt < 4; ++mt) {
                int base = (((kc * 4 + mt) * 2) * 64 + lane) * 8;
                ah[mt] = *(const bf16x8*)&afrag[base];
                al[mt] = *(const bf16x8*)&afrag[base + 512];
            }
            // B fragments from swizzled LDS + truncate-split, 3-pass MFMA
            #pragma unroll
            for (int nt = 0; nt < 4; ++nt) {
                const int c4r = ((nt * 4 + (col0 >> 2)) ^ swz) * 4 + (col0 & 3);
                bf16x8 bh, bl;
                #pragma unroll
                for (int j = 0; j < 8; ++j) {
                    float v = bsw[(quad * 8 + j) * 64 + c4r];
                    unsigned u = __float_as_uint(v);
                    bh[j] = (short)(u >> 16);
                    float lo = v - __uint_as_float(u & 0xffff0000u);
                    bl[j] = (short)(__float_as_uint(lo) >> 16);
                }
                #pragma unroll
                for (int mt = 0; mt < 4; ++mt) {
                    acc[mt][nt] = __builtin_amdgcn_mfma_f32_16x16x32_bf16(
                        ah[mt], bh, acc[mt][nt], 0, 0, 0);
                    acc[mt][nt] = __builtin_amdgcn_mfma_f32_16x16x32_bf16(
                        ah[mt], bl, acc[mt][nt], 0, 0, 0);
                    acc[mt][nt] = __builtin_amdgcn_mfma_f32_16x16x32_bf16(
                        al[mt], bh, acc[mt][nt], 0, 0, 0);
                }
            }
        }
        // end of ng: scores + running min, then reset acc
        #pragma unroll
        for (int nt = 0; nt < 4; ++nt) {
            int kcode = w * 256 + ng * 64 + nt * 16 + col0;
            float cn = cnS[kcode];
            #pragma unroll
            for (int mt = 0; mt < 4; ++mt)
                #pragma unroll
                for (int r = 0; r < 4; ++r) {
                    float s = fmaf(-2.f, acc[mt][nt][r], cn);
                    int slot = mt * 4 + r;
                    if (s < minv[slot]) { minv[slot] = s; mini[slot] = kcode; }
                    acc[mt][nt][r] = 0.f;
                }
        }
    }

    // ---- in-wave argmin reduce (16-lane butterfly over col0), then LDS
    #pragma unroll
    for (int s = 0; s < 16; ++s) {
        float v = minv[s];
        int   ii = mini[s];
        #pragma unroll
        for (int m2 = 1; m2 < 16; m2 <<= 1) {
            float v2 = __shfl_xor(v, m2, 64);
            int   i2 = __shfl_xor(ii, m2, 64);
            if (v2 < v || (v2 == v && i2 < ii)) { v = v2; ii = i2; }
        }
        int row = (s >> 2) * 16 + quad * 4 + (s & 3);
        if (col0 == 0) { redv[row * 4 + w] = v; redi[row * 4 + w] = ii; }
    }
    __syncthreads();
    if (tid < 64) {
        float bv = redv[tid * 4];
        int bi = redi[tid * 4];
        #pragma unroll
        for (int t2 = 1; t2 < 4; ++t2) {
            float v = redv[tid * 4 + t2];
            int ii = redi[tid * 4 + t2];
            if (v < bv || (v == bv && ii < bi)) { bv = v; bi = ii; }
        }
        int m = mask[row0 + tid];
        out[IDX_OFF + row0 + tid] = m ? (float)bi : -1.0f;
        if (m) atomicAdd((float*)&ws[WS_COUNTS + bi], 1.0f);
    }
}

// ---------------------------------------------------------------- kernel 3b
// Epilogue (R11/R12-proven): recompute xb exactly in f32 from x, gather q
// from e rows (L2-cached d_in), write quantized rows, losses.
__global__ __launch_bounds__(256) void k_epi(const float* __restrict__ x,
                                             const float* __restrict__ e,
                                             const float* __restrict__ beta,
                                             const float* __restrict__ ws,
                                             float* __restrict__ out) {
    __shared__ float muS[DIM], scS[DIM], btS[DIM];
    __shared__ int   idxS[64];
    __shared__ float mskS[64];
    __shared__ float wred[4];
    const int tid = threadIdx.x;
    const int row0 = blockIdx.x * 64;

    muS[tid] = ws[WS_MU + tid];
    scS[tid] = ws[WS_SCALE + tid];
    btS[tid] = beta[tid];
    if (tid < 64) {
        float fi = out[IDX_OFF + row0 + tid];
        int m = (fi >= 0.f) ? 1 : 0;
        idxS[tid] = m ? (int)fi : 0;
        mskS[tid] = (float)m;
    }
    __syncthreads();

    float lacc = 0.f;
    float mu = muS[tid], sc = scS[tid], bt = btS[tid];
    const float* erow = e + (size_t)tid * KC;   // feature d = tid
    for (int r = 0; r < 64; ++r) {
        float m = mskS[r];
        float q = (m != 0.f) ? erow[idxS[r]] : 0.f;
        float v = x[(size_t)(row0 + r) * DIM + tid];
        float xb = fmaf(v - mu, sc, bt);
        float diff = xb - q;
        lacc = fmaf(m * diff, diff, lacc);
        nt_st(&out[(size_t)(row0 + r) * DIM + tid], q);
    }
    #pragma unroll
    for (int off = 32; off > 0; off >>= 1) lacc += __shfl_down(lacc, off, 64);
    if ((tid & 63) == 0) wred[tid >> 6] = lacc;
    __syncthreads();
    if (tid == 0)
        atomicAdd((float*)&ws[WS_LOSS], wred[0] + wred[1] + wred[2] + wred[3]);
}

// ---------------------------------------------------------------- kernel 4
__global__ __launch_bounds__(256) void k_final(const float* __restrict__ ws,
                                               float* __restrict__ out) {
    int t = threadIdx.x;
    __shared__ float wr[4];
    float nv = ws[WS_NV];
    float acc = 0.f;
    for (int j = t; j < KC; j += 256) {
        float p = ws[WS_COUNTS + j] / nv;
        acc = fmaf(p, logf(p + 1e-10f), acc);
    }
    #pragma unroll
    for (int off = 32; off > 0; off >>= 1) acc += __shfl_down(acc, off, 64);
    if ((t & 63) == 0) wr[t >> 6] = acc;
    __syncthreads();
    if (t == 0) {
        float ent = wr[0] + wr[1] + wr[2] + wr[3];
        float loss = ws[WS_LOSS] / (nv * (float)DIM);
        out[LOSS0_OFF] = loss;
        out[LOSS1_OFF] = loss;
        out[PERP_OFF] = expf(-ent);
    }
}

// ---------------------------------------------------------------- launch
extern "C" void kernel_launch(void* const* d_in, const int* in_sizes, int n_in,
                              void* d_out, int out_size, void* d_ws, size_t ws_size,
                              hipStream_t stream) {
    const float* x     = (const float*)d_in[0];
    const int*   amask = (const int*)d_in[1];
    const float* e     = (const float*)d_in[2];
    const float* gamma = (const float*)d_in[3];
    const float* beta  = (const float*)d_in[4];
    float* out = (float*)d_out;
    float* ws  = (float*)d_ws;

    (void)hipMemsetAsync(d_ws, 0, 8192, stream);

    k_pre<<<128, 256, 0, stream>>>(x, amask, ws);
    k_finalize<<<5, 256, 0, stream>>>(e, gamma, ws);
    k_main_mfma<<<BN / 64, 256, 0, stream>>>(x, amask, e, beta, ws, out);
    k_epi<<<BN / 64, 256, 0, stream>>>(x, e, beta, ws, out);
    k_final<<<1, 256, 0, stream>>>(ws, out);
}

// Round 14
// 278.551 us; speedup vs baseline: 1.4006x; 1.1523x over previous
//
#include <hip/hip_runtime.h>
#include <math.h>

// Problem constants
#define BN   32768
#define DIM  256
#define KC   1024
#define BN_EPS 1e-5f

// Output layout (floats) in d_out
#define QX_SIZE   (BN * DIM)
#define LOSS0_OFF (QX_SIZE)
#define LOSS1_OFF (QX_SIZE + 1)
#define IDX_OFF   (QX_SIZE + 2)
#define PERP_OFF  (QX_SIZE + 2 + BN)

// Workspace (float offsets) — SMALL SCALARS ONLY (placement law R2..R13:
// only d_in buffers L2-cache; d_ws/d_out reads behave uncached).
#define WS_SUM    0     // 256
#define WS_SUMSQ  256   // 256
#define WS_COUNT  512   // 1
#define WS_LOSS   513   // 1
#define WS_COUNTS 1024  // 1024
#define WS_MU     2048  // 256
#define WS_SCALE  2304  // 256
#define WS_NV     2560  // 1
#define WS_CNORM  3072  // 1024

typedef short bf16x8 __attribute__((ext_vector_type(8)));
typedef float f32x4  __attribute__((ext_vector_type(4)));
typedef float fvec4  __attribute__((ext_vector_type(4)));

static __device__ inline unsigned short f2bf(float f) {
    unsigned int u = __float_as_uint(f);
    return (unsigned short)((u + 0x7FFFu + ((u >> 16) & 1u)) >> 16);
}
static __device__ inline float bf2f(short s) {
    return __uint_as_float(((unsigned int)(unsigned short)s) << 16);
}
static __device__ inline fvec4 nt_ld4(const void* p) {
    return __builtin_nontemporal_load((const fvec4*)p);
}
static __device__ inline void nt_st(float* p, float v) {
    __builtin_nontemporal_store(v, p);
}

// ---------------------------------------------------------------- kernel 1
// Blocks 0..127: masked stats (LDS-reduced). Blocks 128..131: cnorm.
__global__ __launch_bounds__(256) void k_pre(const float* __restrict__ x,
                                             const int* __restrict__ mask,
                                             const float* __restrict__ e,
                                             float* __restrict__ ws) {
    int t = threadIdx.x;
    int b = blockIdx.x;
    if (b >= 128) {
        int k = (b - 128) * 256 + t;
        float acc = 0.f;
        #pragma unroll 8
        for (int d = 0; d < DIM; ++d) {
            float v = e[(size_t)d * KC + k];
            acc = fmaf(v, v, acc);
        }
        ws[WS_CNORM + k] = acc;
        return;
    }
    __shared__ float s4[4 * 256];
    __shared__ float q4[4 * 256];
    __shared__ float cntS[4];
    int c4 = t & 63;
    int rsub = t >> 6;
    float s0=0.f,s1=0.f,s2=0.f,s3=0.f, q0=0.f,q1=0.f,q2=0.f,q3=0.f, cnt=0.f;
    int rbase = b * 4 + rsub;
    for (int i = 0; i < 64; ++i) {
        int r = rbase + i * 512;
        float m = (float)mask[r];
        fvec4 v = nt_ld4(&x[(size_t)r * DIM + c4 * 4]);
        cnt += m;
        float m0 = m*v.x, m1 = m*v.y, m2 = m*v.z, m3 = m*v.w;
        s0 += m0; s1 += m1; s2 += m2; s3 += m3;
        q0 = fmaf(m0, v.x, q0); q1 = fmaf(m1, v.y, q1);
        q2 = fmaf(m2, v.z, q2); q3 = fmaf(m3, v.w, q3);
    }
    int f = c4 * 4;
    s4[rsub * 256 + f + 0] = s0; s4[rsub * 256 + f + 1] = s1;
    s4[rsub * 256 + f + 2] = s2; s4[rsub * 256 + f + 3] = s3;
    q4[rsub * 256 + f + 0] = q0; q4[rsub * 256 + f + 1] = q1;
    q4[rsub * 256 + f + 2] = q2; q4[rsub * 256 + f + 3] = q3;
    if (c4 == 0) cntS[rsub] = cnt;
    __syncthreads();
    float stot = s4[t] + s4[256 + t] + s4[512 + t] + s4[768 + t];
    float qtot = q4[t] + q4[256 + t] + q4[512 + t] + q4[768 + t];
    atomicAdd(&ws[WS_SUM + t], stot);
    atomicAdd(&ws[WS_SUMSQ + t], qtot);
    if (t == 0)
        atomicAdd(&ws[WS_COUNT], cntS[0] + cntS[1] + cntS[2] + cntS[3]);
}

// ---------------------------------------------------------------- kernel 2
__global__ __launch_bounds__(256) void k_finalize(const float* __restrict__ gamma,
                                                  float* __restrict__ ws) {
    int t = threadIdx.x;
    float cnt = ws[WS_COUNT];
    float nv = fmaxf(cnt, 1.f);
    float mu = ws[WS_SUM + t] / nv;
    float var = ws[WS_SUMSQ + t] / nv - mu * mu;
    var = fmaxf(var, 0.f);
    ws[WS_MU + t] = mu;
    ws[WS_SCALE + t] = rsqrtf(var + BN_EPS) * gamma[t];
    if (t == 0) ws[WS_NV] = nv;
}

// ---------------------------------------------------------------- kernel 3
// MFMA main, R14: 512 threads (8 waves -> 2 waves/SIMD), 64 rows/block,
// grid 512. A in-kernel from x; B wave-private LDS from e (coalesced,
// XOR-swizzled, ring-2 depth-2 prefetch); fused epilogue (xb from afrag
// hi+lo reconstruction — R8-verified — q gathered from L2-hot e).
__global__ __launch_bounds__(512, 2) void k_main_mfma(
        const float* __restrict__ x, const int* __restrict__ mask,
        const float* __restrict__ e, const float* __restrict__ beta,
        const float* __restrict__ ws, float* __restrict__ out) {
    __shared__ __align__(16) short afrag[8 * 4 * 2 * 64 * 8];   // 64 KB
    __shared__ __align__(16) float Bs[8][2048];                 // 64 KB
    __shared__ float muS[DIM], scS[DIM], btS[DIM];
    __shared__ float cnS[KC];
    __shared__ float redv[64 * 8];
    __shared__ int   redi[64 * 8];
    __shared__ int   idxS[64];
    __shared__ float mskS[64];
    __shared__ float wred[8];

    const int tid = threadIdx.x;
    const int row0 = blockIdx.x * 64;
    const int w = tid >> 6;          // 0..7
    const int lane = tid & 63;
    const int quad = lane >> 4;
    const int col0 = lane & 15;

    if (tid < 256) {
        muS[tid] = ws[WS_MU + tid];
        scS[tid] = ws[WS_SCALE + tid];
        btS[tid] = beta[tid];
    }
    #pragma unroll
    for (int p = 0; p < 2; ++p)
        cnS[p * 512 + tid] = ws[WS_CNORM + p * 512 + tid];
    __syncthreads();

    // ---- stage A-fragments: wave w stages mtile w>>1, kc-half w&1
    {
        const int mt = w >> 1;
        const float* xr = x + (size_t)(row0 + mt * 16 + col0) * DIM;
        const int kq = quad * 8;
        #pragma unroll
        for (int kk = 0; kk < 4; ++kk) {
            int kc = (w & 1) * 4 + kk;
            int k0 = kc * 32 + kq;
            fvec4 v0 = nt_ld4(xr + k0);
            fvec4 v1 = nt_ld4(xr + k0 + 4);
            float xv[8] = {v0.x, v0.y, v0.z, v0.w, v1.x, v1.y, v1.z, v1.w};
            bf16x8 hv, lv;
            #pragma unroll
            for (int j = 0; j < 8; ++j) {
                float xb = fmaf(xv[j] - muS[k0 + j], scS[k0 + j], btS[k0 + j]);
                unsigned short h = f2bf(xb);
                float hf = __uint_as_float((unsigned)h << 16);
                hv[j] = (short)h;
                lv[j] = (short)f2bf(xb - hf);
            }
            int base = (((kc * 4 + mt) * 2) * 64 + lane) * 8;
            *(bf16x8*)&afrag[base] = hv;
            *(bf16x8*)&afrag[base + 512] = lv;
        }
    }
    __syncthreads();

    const fvec4* e4 = (const fvec4*)e;   // 256 fvec4 per d-row
    const int swz = (quad & 1) * 4;
    float* bsw = &Bs[w][0];

    float minv[16];
    int   mini[16];
    #pragma unroll
    for (int i = 0; i < 16; ++i) { minv[i] = 3.4e38f; mini[i] = 0; }

    // wave w: codes w*128 .. w*128+127, chunks ci = ng2*8+kc (16 chunks),
    // each chunk = 32 k-rows x 64 codes. Ring-2 regs, depth-2 prefetch.
    fvec4 raw[2][8];
    #pragma unroll
    for (int p = 0; p < 8; ++p) {
        int f = p * 64 + lane;
        raw[0][p] = e4[(size_t)(f >> 4) * 256 + w * 32 + (f & 15)];        // ci=0
        raw[1][p] = e4[(size_t)(32 + (f >> 4)) * 256 + w * 32 + (f & 15)]; // ci=1
    }

    f32x4 acc[4][4];
    #pragma unroll
    for (int mt = 0; mt < 4; ++mt)
        #pragma unroll
        for (int nt = 0; nt < 4; ++nt)
            acc[mt][nt] = (f32x4){0.f, 0.f, 0.f, 0.f};

    #pragma unroll
    for (int ng2 = 0; ng2 < 2; ++ng2) {
        #pragma unroll
        for (int kc = 0; kc < 8; ++kc) {
            const int ci = ng2 * 8 + kc;
            const int buf = ci & 1;
            // commit chunk ci to wave-private LDS (XOR-swizzled slots)
            {
                fvec4* b4 = (fvec4*)bsw;
                #pragma unroll
                for (int p = 0; p < 8; ++p) {
                    int f = p * 64 + lane;
                    int row = f >> 4;
                    int c4 = f & 15;
                    b4[row * 16 + (c4 ^ (((row >> 3) & 1) * 4))] = raw[buf][p];
                }
            }
            // depth-2 prefetch into the buffer just consumed
            if (ci + 2 < 16) {
                const int nci = ci + 2;
                const int nng = nci >> 3, nkc = nci & 7;
                #pragma unroll
                for (int p = 0; p < 8; ++p) {
                    int f = p * 64 + lane;
                    raw[buf][p] =
                        e4[(size_t)(nkc * 32 + (f >> 4)) * 256 + w * 32 + nng * 16 + (f & 15)];
                }
            }
            // A fragments for this kc
            bf16x8 ah[4], al[4];
            #pragma unroll
            for (int mt = 0; mt < 4; ++mt) {
                int base = (((kc * 4 + mt) * 2) * 64 + lane) * 8;
                ah[mt] = *(const bf16x8*)&afrag[base];
                al[mt] = *(const bf16x8*)&afrag[base + 512];
            }
            // B fragments from swizzled LDS + truncate-split, 3-pass MFMA
            #pragma unroll
            for (int nt = 0; nt < 4; ++nt) {
                const int c4r = ((nt * 4 + (col0 >> 2)) ^ swz) * 4 + (col0 & 3);
                bf16x8 bh, bl;
                #pragma unroll
                for (int j = 0; j < 8; ++j) {
                    float v = bsw[(quad * 8 + j) * 64 + c4r];
                    unsigned u = __float_as_uint(v);
                    bh[j] = (short)(u >> 16);
                    float lo = v - __uint_as_float(u & 0xffff0000u);
                    bl[j] = (short)(__float_as_uint(lo) >> 16);
                }
                #pragma unroll
                for (int mt = 0; mt < 4; ++mt) {
                    acc[mt][nt] = __builtin_amdgcn_mfma_f32_16x16x32_bf16(
                        ah[mt], bh, acc[mt][nt], 0, 0, 0);
                    acc[mt][nt] = __builtin_amdgcn_mfma_f32_16x16x32_bf16(
                        ah[mt], bl, acc[mt][nt], 0, 0, 0);
                    acc[mt][nt] = __builtin_amdgcn_mfma_f32_16x16x32_bf16(
                        al[mt], bh, acc[mt][nt], 0, 0, 0);
                }
            }
        }
        // end of ng2: scores + running min, reset acc
        #pragma unroll
        for (int nt = 0; nt < 4; ++nt) {
            int kcode = w * 128 + ng2 * 64 + nt * 16 + col0;
            float cn = cnS[kcode];
            #pragma unroll
            for (int mt = 0; mt < 4; ++mt)
                #pragma unroll
                for (int r = 0; r < 4; ++r) {
                    float s = fmaf(-2.f, acc[mt][nt][r], cn);
                    int slot = mt * 4 + r;
                    if (s < minv[slot]) { minv[slot] = s; mini[slot] = kcode; }
                    acc[mt][nt][r] = 0.f;
                }
        }
    }

    // ---- in-wave argmin reduce (16-lane butterfly over col0), then LDS
    #pragma unroll
    for (int s = 0; s < 16; ++s) {
        float v = minv[s];
        int   ii = mini[s];
        #pragma unroll
        for (int m2 = 1; m2 < 16; m2 <<= 1) {
            float v2 = __shfl_xor(v, m2, 64);
            int   i2 = __shfl_xor(ii, m2, 64);
            if (v2 < v || (v2 == v && i2 < ii)) { v = v2; ii = i2; }
        }
        int row = (s >> 2) * 16 + quad * 4 + (s & 3);
        if (col0 == 0) { redv[row * 8 + w] = v; redi[row * 8 + w] = ii; }
    }
    __syncthreads();
    if (tid < 64) {
        float bv = redv[tid * 8];
        int bi = redi[tid * 8];
        #pragma unroll
        for (int t2 = 1; t2 < 8; ++t2) {
            float v = redv[tid * 8 + t2];
            int ii = redi[tid * 8 + t2];
            if (v < bv || (v == bv && ii < bi)) { bv = v; bi = ii; }
        }
        int m = mask[row0 + tid];
        idxS[tid] = bi;
        mskS[tid] = (float)m;
        out[IDX_OFF + row0 + tid] = m ? (float)bi : -1.0f;
        if (m) atomicAdd((float*)&ws[WS_COUNTS + bi], 1.0f);
    }
    __syncthreads();

    // ---- fused epilogue: d = tid&255, rows (tid>>8)*32 .. +31
    {
        const int d = tid & 255;
        const int rbase2 = (tid >> 8) * 32;
        const int ekc = d >> 5;
        const int equad = (d >> 3) & 3;
        const int ej = d & 7;
        const float* erow = e + (size_t)d * KC;
        float lacc = 0.f;
        for (int rr = 0; rr < 32; ++rr) {
            int r = rbase2 + rr;
            float m = mskS[r];
            float q = (m != 0.f) ? erow[idxS[r]] : 0.f;
            int off = (((ekc * 4 + (r >> 4)) * 2) * 64 + equad * 16 + (r & 15)) * 8 + ej;
            float xb = bf2f(afrag[off]) + bf2f(afrag[off + 512]);
            float diff = xb - q;
            lacc = fmaf(m * diff, diff, lacc);
            nt_st(&out[(size_t)(row0 + r) * DIM + d], q);
        }
        #pragma unroll
        for (int off2 = 32; off2 > 0; off2 >>= 1)
            lacc += __shfl_down(lacc, off2, 64);
        if (lane == 0) wred[w] = lacc;
    }
    __syncthreads();
    if (tid == 0) {
        float s = 0.f;
        #pragma unroll
        for (int i = 0; i < 8; ++i) s += wred[i];
        atomicAdd((float*)&ws[WS_LOSS], s);
    }
}

// ---------------------------------------------------------------- kernel 4
__global__ __launch_bounds__(256) void k_final(const float* __restrict__ ws,
                                               float* __restrict__ out) {
    int t = threadIdx.x;
    __shared__ float wr[4];
    float nv = ws[WS_NV];
    float acc = 0.f;
    for (int j = t; j < KC; j += 256) {
        float p = ws[WS_COUNTS + j] / nv;
        acc = fmaf(p, logf(p + 1e-10f), acc);
    }
    #pragma unroll
    for (int off = 32; off > 0; off >>= 1) acc += __shfl_down(acc, off, 64);
    if ((t & 63) == 0) wr[t >> 6] = acc;
    __syncthreads();
    if (t == 0) {
        float ent = wr[0] + wr[1] + wr[2] + wr[3];
        float loss = ws[WS_LOSS] / (nv * (float)DIM);
        out[LOSS0_OFF] = loss;
        out[LOSS1_OFF] = loss;
        out[PERP_OFF] = expf(-ent);
    }
}

// ---------------------------------------------------------------- launch
extern "C" void kernel_launch(void* const* d_in, const int* in_sizes, int n_in,
                              void* d_out, int out_size, void* d_ws, size_t ws_size,
                              hipStream_t stream) {
    const float* x     = (const float*)d_in[0];
    const int*   amask = (const int*)d_in[1];
    const float* e     = (const float*)d_in[2];
    const float* gamma = (const float*)d_in[3];
    const float* beta  = (const float*)d_in[4];
    float* out = (float*)d_out;
    float* ws  = (float*)d_ws;

    (void)hipMemsetAsync(d_ws, 0, 8192, stream);

    k_pre<<<132, 256, 0, stream>>>(x, amask, e, ws);
    k_finalize<<<1, 256, 0, stream>>>(gamma, ws);
    k_main_mfma<<<BN / 64, 512, 0, stream>>>(x, amask, e, beta, ws, out);
    k_final<<<1, 256, 0, stream>>>(ws, out);
}